// Round 7
// baseline (302.438 us; speedup 1.0000x reference)
//
#include <hip/hip_runtime.h>
#include <hip/hip_bf16.h>

#define T_ 4
#define B_ 4
#define C_ 256
#define H_ 32
#define W_ 32
#define TB_ 16
#define Hh_ 16
#define Wh_ 16
#define INVS2 0.70710678118654752440f
#define EPSBN 1e-5f
#define NBLK 512

// Canonical weight arena offsets (bf16 elements)
#define OFF_HW   0
#define OFF_W1   4096
#define OFF_B1   4352
#define OFF_W2   4368
#define OFF_B2   6672
#define OFF_G1   6688
#define OFF_BE1  7200
#define OFF_G2   7712
#define OFF_BE2  8736
#define OFF_G3   9760
#define OFF_BE3  10016
#define OFF_G4   10272
#define OFF_BE4  10528
#define OFF_G5   10784
#define OFF_BE5  11040
#define W_TOTAL  11296
// stats arena (floats): sums1[1024] | sums2[2048] | sums345[1536]
#define NSUMS    4608

struct WPtrs { const void* p[15]; };

typedef __attribute__((ext_vector_type(8))) short short8;
typedef __attribute__((ext_vector_type(4))) float f32x4;

__device__ inline float bf2f(__hip_bfloat16 v) { return __bfloat162float(v); }
__device__ inline float bfu(unsigned short u) { return __uint_as_float((unsigned)u << 16); }

// ---------------------------------------------------------------------------
// k_init: sniff dtype, convert weights to bf16 arena, zero sums + barrier.
// ---------------------------------------------------------------------------
__global__ __launch_bounds__(256) void k_init(const unsigned short* __restrict__ xr,
                                              WPtrs wp,
                                              __hip_bfloat16* __restrict__ wc,
                                              float* __restrict__ sums,
                                              int* __restrict__ bar,
                                              int* __restrict__ flag) {
    int tid = threadIdx.x;
    int cnt = 0;
    for (int i = tid; i < 2048; i += 256) {
        int e = (xr[i] >> 7) & 0xFF;
        if (e >= 134) cnt++;
    }
    for (int o = 1; o < 64; o <<= 1) cnt += __shfl_xor(cnt, o, 64);
    __shared__ int sh[4];
    if ((tid & 63) == 0) sh[tid >> 6] = cnt;
    __syncthreads();
    int f = (sh[0] + sh[1] + sh[2] + sh[3] >= 32) ? 1 : 0;
    if (blockIdx.x == 0 && tid == 0) *flag = f;

    const int sizes[15] = {4096, 256, 16, 2304, 16, 512, 512, 1024, 1024,
                           256, 256, 256, 256, 256, 256};
    int i = blockIdx.x * 256 + tid;
    if (i < W_TOTAL) {
        int seg = 0, off = 0;
        while (i >= off + sizes[seg]) { off += sizes[seg]; seg++; }
        int j = i - off;
        float v = f ? ((const float*)wp.p[seg])[j]
                    : bf2f(((const __hip_bfloat16*)wp.p[seg])[j]);
        wc[i] = __float2bfloat16(v);
    }
    if (i < NSUMS) sums[i] = 0.f;
    if (i < 16) bar[i] = 0;
}

// ---------------------------------------------------------------------------
// Device-wide barrier (monotonic counters, 8-way split arrivals).
// Requires all NBLK blocks co-resident (guaranteed: LDS 39KB -> 4 blk/CU,
// launch_bounds(256,2) -> >=2 blk/CU; 256 CU * 2 >= 512).
// ---------------------------------------------------------------------------
__device__ __forceinline__ void gbar(int* bs, int phase) {
    __syncthreads();
    if (threadIdx.x == 0) {
        __threadfence();
        int t = atomicAdd(&bs[2 + (blockIdx.x & 7)], 1) + 1;
        if (t == phase * (NBLK / 8)) {
            int m = atomicAdd(&bs[1], 1) + 1;
            if (m == phase * 8) atomicAdd(&bs[0], 1);
        }
        while (atomicAdd(&bs[0], 0) < phase) __builtin_amdgcn_s_sleep(2);
        __threadfence();
    }
    __syncthreads();
}

// ---------------------------------------------------------------------------
// Shared-memory union across phases.
// ---------------------------------------------------------------------------
struct SM {
    union {
        struct {
            short lo[1025 * 8];            // channel-last bf16, d 0..7 (+zero row)
            short hi[1025 * 8];            // d 8..15
            unsigned short w2s[2304];      // [k][d*9+tap]
            unsigned short w1s[256];       // [k][d]
            unsigned short bs[32];         // B1 | B2
            float parts[4][4][16];         // [wv][g][r*4+which]
        } cv;
        struct {
            float wt[4][16][16];           // [q][d][k]
            float bsc[64], bsh[64];
            float parts2[4][32];
        } mi;
        float p48[4][8];                   // lifhaar / stage2 partials
    };
};

// ---------------------------------------------------------------------------
// k_fused: 4 phases separated by device-wide barriers.
//   P1 lifhaar (2048 units, 4/blk)  P2 stage2 (4096 units, 8/blk)
//   P3 conv (256) | mixinv (256)    P4 final (2048 units, 4/blk)
// ---------------------------------------------------------------------------
__global__ __launch_bounds__(256, 2) void k_fused(const void* __restrict__ x_,
                                                  const __hip_bfloat16* __restrict__ wc,
                                                  float* __restrict__ stats,
                                                  int* __restrict__ bar,
                                                  const int* __restrict__ flag,
                                                  unsigned char* __restrict__ s,
                                                  __hip_bfloat16* __restrict__ l2,
                                                  __hip_bfloat16* __restrict__ rec,
                                                  __hip_bfloat16* __restrict__ c1,
                                                  __hip_bfloat16* __restrict__ c2,
                                                  void* __restrict__ out_) {
    __shared__ SM sm;
    int bid = blockIdx.x;
    int tid = threadIdx.x;
    int lane = tid & 63, wv = tid >> 6;
    int f = *flag;

    // ======================= Phase 1: LIF + Haar-W =======================
    {
        const float* xf = (const float*)x_;
        const unsigned int* xb = (const unsigned int*)x_;
        for (int u = bid * 4; u < bid * 4 + 4; ++u) {
            int half = u & 1;
            int c = (u >> 1) & 255;
            int b = u >> 9;
            int wp = tid & 15;
            int h = half * 16 + (tid >> 4);
            int n = ((b * 256 + c) * 32 + h) * 32 + 2 * wp;

            float v0 = 0.f, v1 = 0.f;
            float aL = 0.f, qL = 0.f, aH = 0.f, qH = 0.f;
            #pragma unroll
            for (int t = 0; t < T_; ++t) {
                size_t idx = (size_t)t * 1048576 + n;
                float x0, x1;
                if (f) {
                    float2 xx = *(const float2*)(xf + idx);
                    x0 = xx.x; x1 = xx.y;
                } else {
                    unsigned int uu = xb[idx >> 1];
                    x0 = __uint_as_float(uu << 16);
                    x1 = __uint_as_float(uu & 0xffff0000u);
                }
                v0 += (x0 - v0) * 0.5f;
                v1 += (x1 - v1) * 0.5f;
                float s0 = (v0 >= 1.f) ? 1.f : 0.f;
                float s1 = (v1 >= 1.f) ? 1.f : 0.f;
                v0 *= (1.f - s0);
                v1 *= (1.f - s1);
                int tb = t * 4 + b;
                ((uchar2*)s)[(size_t)(tb * 256 + c) * 512 + h * 16 + wp] =
                    make_uchar2((unsigned char)s0, (unsigned char)s1);
                float cl = s0 + s1, ch = s0 - s1;
                aL += cl; qL += cl * cl; aH += ch; qH += ch * ch;
            }
            for (int o = 1; o < 64; o <<= 1) {
                aL += __shfl_xor(aL, o, 64); qL += __shfl_xor(qL, o, 64);
                aH += __shfl_xor(aH, o, 64); qH += __shfl_xor(qH, o, 64);
            }
            if (lane == 0) {
                sm.p48[wv][0] = aL; sm.p48[wv][1] = qL;
                sm.p48[wv][2] = aH; sm.p48[wv][3] = qH;
            }
            __syncthreads();
            if (tid < 4) {
                float tot = sm.p48[0][tid] + sm.p48[1][tid] + sm.p48[2][tid] + sm.p48[3][tid];
                const int offs[4] = {0, 512, 256, 768};
                atomicAdd(&stats[offs[tid] + c], tot);
            }
            __syncthreads();
        }
    }
    gbar(bar, 1);

    // ======================= Phase 2: stage2 =======================
    {
        float* sums2 = stats + 1024;
        for (int u = bid * 8; u < bid * 8 + 8; ++u) {
            int c = u & 255;
            int tb = u >> 8;

            const float nrm = 1.f / 8192.f;
            float mL = stats[c] * INVS2 * nrm;
            float vL = fmaxf(stats[512 + c] * 0.5f * nrm - mL * mL, 0.f);
            float sL = bf2f(wc[OFF_G1 + c]) * rsqrtf(vL + EPSBN);
            float tL = bf2f(wc[OFF_BE1 + c]) - mL * sL;
            float mH = stats[256 + c] * INVS2 * nrm;
            float vH = fmaxf(stats[768 + c] * 0.5f * nrm - mH * mH, 0.f);
            float sH = bf2f(wc[OFF_G1 + 256 + c]) * rsqrtf(vH + EPSBN);
            float tH = bf2f(wc[OFF_BE1 + 256 + c]) - mH * sH;
            float slo = sL * INVS2, shi = sH * INVS2;

            int w = tid & 15, v = tid >> 4;
            const uchar2* sp = (const uchar2*)(s + ((size_t)(tb * 256 + c)) * 1024);
            uchar2 pa = sp[(2 * v) * 16 + w];
            uchar2 pb = sp[(2 * v + 1) * 16 + w];
            float lt = (float)(pa.x + pa.y) * slo + tL;
            float lb = (float)(pb.x + pb.y) * slo + tL;
            float ht = (float)((int)pa.x - (int)pa.y) * shi + tH;
            float hb = (float)((int)pb.x - (int)pb.y) * shi + tH;

            float zLL = (lt + lb) * INVS2;
            float zHL = (lt - lb) * INVS2;
            float zLH = (ht + hb) * INVS2;
            float zHH = (ht - hb) * INVS2;
            zLL = (fabsf(zLL) - 0.5f >= 0.f) ? zLL : 0.f;
            zHL = (fabsf(zHL) - 0.5f >= 0.f) ? zHL : 0.f;
            zLH = (fabsf(zLH) - 0.5f >= 0.f) ? zLH : 0.f;
            zHH = (fabsf(zHH) - 0.5f >= 0.f) ? zHH : 0.f;

            float r0 = zLL, r1 = zHL, r2 = zLH, r3 = zHH;
            float q0 = zLL * zLL, q1 = zHL * zHL, q2 = zLH * zLH, q3 = zHH * zHH;
            for (int o = 1; o < 64; o <<= 1) {
                r0 += __shfl_xor(r0, o, 64); r1 += __shfl_xor(r1, o, 64);
                r2 += __shfl_xor(r2, o, 64); r3 += __shfl_xor(r3, o, 64);
                q0 += __shfl_xor(q0, o, 64); q1 += __shfl_xor(q1, o, 64);
                q2 += __shfl_xor(q2, o, 64); q3 += __shfl_xor(q3, o, 64);
            }
            if (lane == 0) {
                sm.p48[wv][0] = r0; sm.p48[wv][1] = r1; sm.p48[wv][2] = r2; sm.p48[wv][3] = r3;
                sm.p48[wv][4] = q0; sm.p48[wv][5] = q1; sm.p48[wv][6] = q2; sm.p48[wv][7] = q3;
            }
            __syncthreads();
            float S0 = sm.p48[0][0] + sm.p48[1][0] + sm.p48[2][0] + sm.p48[3][0];
            float S1 = sm.p48[0][1] + sm.p48[1][1] + sm.p48[2][1] + sm.p48[3][1];
            float S2 = sm.p48[0][2] + sm.p48[1][2] + sm.p48[2][2] + sm.p48[3][2];
            float S3 = sm.p48[0][3] + sm.p48[1][3] + sm.p48[2][3] + sm.p48[3][3];
            float Q0 = sm.p48[0][4] + sm.p48[1][4] + sm.p48[2][4] + sm.p48[3][4];
            float Q1 = sm.p48[0][5] + sm.p48[1][5] + sm.p48[2][5] + sm.p48[3][5];
            float Q2 = sm.p48[0][6] + sm.p48[1][6] + sm.p48[2][6] + sm.p48[3][6];
            float Q3 = sm.p48[0][7] + sm.p48[1][7] + sm.p48[2][7] + sm.p48[3][7];
            float fLL = (Q0 * (1.f / 256.f) > 0.01f) ? 1.f : 0.f;
            float fHL = (Q1 * (1.f / 256.f) > 0.02f) ? 1.f : 0.f;
            float fLH = (Q2 * (1.f / 256.f) > 0.02f) ? 1.f : 0.f;
            float fHH = (Q3 * (1.f / 256.f) > 0.05f) ? 1.f : 0.f;

            if (tid < 8) {
                const int cho[8] = {0, 1024, 256, 1280, 512, 1536, 768, 1792};
                const float vals[8] = {fLL * S0, fLL * Q0, fHL * S1, fHL * Q1,
                                       fLH * S2, fLH * Q2, fHH * S3, fHH * Q3};
                atomicAdd(&sums2[cho[tid] + c], vals[tid]);
            }

            size_t ob = (((size_t)tb * 1024) + c) * 256 + tid;
            l2[ob]               = __float2bfloat16(zLL * fLL);
            l2[ob + 256u * 256u] = __float2bfloat16(zHL * fHL);
            l2[ob + 512u * 256u] = __float2bfloat16(zLH * fLH);
            l2[ob + 768u * 256u] = __float2bfloat16(zHH * fHH);
            __syncthreads();
        }
    }
    gbar(bar, 2);

    // ======================= Phase 3: conv | mixinv =======================
    if (bid < 256) {
        int img = bid;
        const unsigned short* wr = (const unsigned short*)wc;
        for (int i = tid; i < 2304; i += 256) sm.cv.w2s[i] = wr[OFF_W2 + i];
        sm.cv.w1s[tid] = wr[OFF_W1 + tid];
        if (tid < 16) { sm.cv.bs[tid] = wr[OFF_B1 + tid]; sm.cv.bs[16 + tid] = wr[OFF_B2 + tid]; }
        if (tid < 8) {
            ((unsigned int*)sm.cv.lo)[4096 + (tid & 3)] = 0;
            ((unsigned int*)sm.cv.hi)[4096 + (tid & 3)] = 0;
        }
        {
            const unsigned int* sp = (const unsigned int*)(s + (size_t)img * 16384);
            int d2 = tid >> 5;
            int pg = tid & 31;
            unsigned int* dst = (unsigned int*)((d2 < 4) ? sm.cv.lo : sm.cv.hi);
            int dl = d2 & 3;
            #pragma unroll
            for (int p = 0; p < 8; ++p) {
                int base = p * 32 + pg;
                unsigned int u0 = sp[d2 * 512 + base];
                unsigned int u1 = sp[d2 * 512 + 256 + base];
                #pragma unroll
                for (int jj = 0; jj < 4; ++jj) {
                    int j = (jj + pg) & 3;
                    unsigned int b0 = (u0 >> (8 * j)) & 255u;
                    unsigned int b1 = (u1 >> (8 * j)) & 255u;
                    unsigned int val = (b0 ? 0x3F80u : 0u) | ((b1 ? 0x3F80u : 0u) << 16);
                    int pix = p * 128 + pg * 4 + j;
                    dst[pix * 4 + dl] = val;
                }
            }
        }
        __syncthreads();

        int m = lane & 15;
        int g = lane >> 4;
        const int tapA[5] = {0, 2, 4, 6, 8};
        const int tapB[5] = {1, 3, 5, 7, 8};

        short8 afr[5], a1f;
        #pragma unroll
        for (int p = 0; p < 5; ++p) {
            int tap = (g < 2) ? tapA[p] : tapB[p];
            short8 av;
            #pragma unroll
            for (int j = 0; j < 8; ++j) {
                int d = (g & 1) * 8 + j;
                unsigned short w = sm.cv.w2s[m * 144 + d * 9 + tap];
                if (p == 4 && g >= 2) w = 0;
                av[j] = (short)w;
            }
            afr[p] = av;
        }
        #pragma unroll
        for (int j = 0; j < 8; ++j) {
            int d = (g & 1) * 8 + j;
            a1f[j] = (g < 2) ? (short)sm.cv.w1s[m * 16 + d] : (short)0;
        }
        float bias1[4], bias2[4];
        #pragma unroll
        for (int r = 0; r < 4; ++r) {
            bias1[r] = bfu(sm.cv.bs[g * 4 + r]);
            bias2[r] = bfu(sm.cv.bs[16 + g * 4 + r]);
        }

        __hip_bfloat16* o1 = c1 + (size_t)img * 16384;
        __hip_bfloat16* o2 = c2 + (size_t)img * 16384;
        const short* bsrc = (g & 1) ? sm.cv.hi : sm.cv.lo;

        float cs1[4] = {0, 0, 0, 0}, cq1[4] = {0, 0, 0, 0};
        float cs2[4] = {0, 0, 0, 0}, cq2[4] = {0, 0, 0, 0};

        for (int t = wv * 16; t < wv * 16 + 16; ++t) {
            int h = t >> 1;
            int w0 = (t & 1) << 4;
            f32x4 acc2 = {0.f, 0.f, 0.f, 0.f};
            f32x4 acc1 = {0.f, 0.f, 0.f, 0.f};
            #pragma unroll
            for (int p = 0; p < 5; ++p) {
                int tap = (g < 2) ? tapA[p] : tapB[p];
                int row = h + tap / 3 - 1;
                int col = w0 + m + (tap % 3) - 1;
                bool ok = ((unsigned)row < 32u) && ((unsigned)col < 32u);
                int idx = ok ? (row * 32 + col) : 1024;
                short8 bv = *(const short8*)&bsrc[idx * 8];
                acc2 = __builtin_amdgcn_mfma_f32_16x16x32_bf16(afr[p], bv, acc2, 0, 0, 0);
                if (p == 2)
                    acc1 = __builtin_amdgcn_mfma_f32_16x16x32_bf16(a1f, bv, acc1, 0, 0, 0);
            }
            int pix = h * 32 + w0 + m;
            #pragma unroll
            for (int r = 0; r < 4; ++r) {
                int k = g * 4 + r;
                float y1 = acc1[r] + bias1[r];
                float y2 = acc2[r] + bias2[r];
                o1[(size_t)k * 1024 + pix] = __float2bfloat16(y1);
                o2[(size_t)k * 1024 + pix] = __float2bfloat16(y2);
                cs1[r] += y1; cq1[r] += y1 * y1;
                cs2[r] += y2; cq2[r] += y2 * y2;
            }
        }
        #pragma unroll
        for (int o = 1; o < 16; o <<= 1) {
            #pragma unroll
            for (int r = 0; r < 4; ++r) {
                cs1[r] += __shfl_xor(cs1[r], o, 64);
                cq1[r] += __shfl_xor(cq1[r], o, 64);
                cs2[r] += __shfl_xor(cs2[r], o, 64);
                cq2[r] += __shfl_xor(cq2[r], o, 64);
            }
        }
        if (m == 0) {
            #pragma unroll
            for (int r = 0; r < 4; ++r) {
                sm.cv.parts[wv][g][r * 4 + 0] = cs1[r];
                sm.cv.parts[wv][g][r * 4 + 1] = cq1[r];
                sm.cv.parts[wv][g][r * 4 + 2] = cs2[r];
                sm.cv.parts[wv][g][r * 4 + 3] = cq2[r];
            }
        }
        __syncthreads();
        if (tid < 64) {
            int gg = tid >> 4, r = (tid >> 2) & 3, which = tid & 3;
            float tot = sm.cv.parts[0][gg][r * 4 + which] + sm.cv.parts[1][gg][r * 4 + which]
                      + sm.cv.parts[2][gg][r * 4 + which] + sm.cv.parts[3][gg][r * 4 + which];
            int ch = (img & 15) * 16 + gg * 4 + r;
            const int base[4] = {3584, 3840, 4096, 4352};
            atomicAdd(&stats[base[which] + ch], tot);
        }
    } else {
        int mb = bid - 256;
        int cg = mb & 15;
        int tb = mb >> 4;
        const float* sums2 = stats + 1024;

        for (int i = tid; i < 1024; i += 256) {
            int q = i >> 8, rem = i & 255, d = rem >> 4, k = rem & 15;
            int nb = q * 4 + (cg >> 2);
            sm.mi.wt[q][d][k] = bf2f(wc[OFF_HW + nb * 256 + d * 16 + k]);
        }
        if (tid < 64) {
            int q = tid >> 4, d = tid & 15;
            int ch = q * 256 + cg * 16 + d;
            float m = sums2[ch] * (1.f / 4096.f);
            float var = fmaxf(sums2[1024 + ch] * (1.f / 4096.f) - m * m, 0.f);
            float sc = bf2f(wc[OFF_G2 + ch]) * rsqrtf(var + EPSBN);
            sm.mi.bsc[tid] = sc;
            sm.mi.bsh[tid] = bf2f(wc[OFF_BE2 + ch]) - m * sc;
        }
        __syncthreads();

        float h[4][16];
        #pragma unroll
        for (int q = 0; q < 4; ++q)
            #pragma unroll
            for (int k = 0; k < 16; ++k) h[q][k] = 0.f;

        int p = tid;
        #pragma unroll
        for (int q = 0; q < 4; ++q) {
            const __hip_bfloat16* base =
                l2 + ((size_t)tb * 1024 + q * 256 + cg * 16) * 256 + p;
            #pragma unroll
            for (int d = 0; d < 16; ++d) {
                float xv = bf2f(base[d * 256]) * sm.mi.bsc[q * 16 + d] + sm.mi.bsh[q * 16 + d];
                #pragma unroll
                for (int k = 0; k < 16; ++k)
                    h[q][k] = fmaf(xv, sm.mi.wt[q][d][k], h[q][k]);
            }
        }

        int uh = tid >> 4, uw = tid & 15;
        __hip_bfloat16* ob = rec + ((size_t)tb * 256 + cg * 16) * 1024;
        float sk[16], qk[16];
        #pragma unroll
        for (int k = 0; k < 16; ++k) {
            float LL = h[0][k], HL = h[1][k], LH = h[2][k], HH = h[3][k];
            float v00 = 0.5f * (LL + HL + LH + HH);
            float v01 = 0.5f * (LL + HL - LH - HH);
            float v10 = 0.5f * (LL - HL + LH - HH);
            float v11 = 0.5f * (LL - HL - LH + HH);
            __hip_bfloat162 top, bot;
            top.x = __float2bfloat16(v00); top.y = __float2bfloat16(v01);
            bot.x = __float2bfloat16(v10); bot.y = __float2bfloat16(v11);
            *(__hip_bfloat162*)(ob + (size_t)k * 1024 + (2 * uh) * 32 + 2 * uw) = top;
            *(__hip_bfloat162*)(ob + (size_t)k * 1024 + (2 * uh + 1) * 32 + 2 * uw) = bot;
            sk[k] = v00 + v01 + v10 + v11;
            qk[k] = v00 * v00 + v01 * v01 + v10 * v10 + v11 * v11;
        }
        for (int o = 1; o < 64; o <<= 1) {
            #pragma unroll
            for (int k = 0; k < 16; ++k) {
                sk[k] += __shfl_xor(sk[k], o, 64);
                qk[k] += __shfl_xor(qk[k], o, 64);
            }
        }
        if (lane == 0) {
            #pragma unroll
            for (int k = 0; k < 16; ++k) {
                sm.mi.parts2[wv][k * 2]     = sk[k];
                sm.mi.parts2[wv][k * 2 + 1] = qk[k];
            }
        }
        __syncthreads();
        if (tid < 32) {
            int k = tid >> 1, which = tid & 1;
            float tot = sm.mi.parts2[0][tid] + sm.mi.parts2[1][tid]
                      + sm.mi.parts2[2][tid] + sm.mi.parts2[3][tid];
            atomicAdd(&stats[3072 + which * 256 + cg * 16 + k], tot);
        }
    }
    gbar(bar, 3);

    // ======================= Phase 4: final =======================
    {
        const float inv = 1.f / 16384.f;
        #pragma unroll
        for (int i = 0; i < 4; ++i) {
            int n8 = bid * 1024 + i * 256 + tid;
            int c = ((n8 * 8) >> 10) & 255;
            float m3 = stats[3072 + c] * inv;
            float v3 = fmaxf(stats[3328 + c] * inv - m3 * m3, 0.f);
            float sc3 = bf2f(wc[OFF_G3 + c]) * rsqrtf(v3 + EPSBN);
            float sh3 = bf2f(wc[OFF_BE3 + c]) - m3 * sc3;
            float m4 = stats[3584 + c] * inv;
            float v4 = fmaxf(stats[3840 + c] * inv - m4 * m4, 0.f);
            float sc4 = bf2f(wc[OFF_G4 + c]) * rsqrtf(v4 + EPSBN);
            float sh4 = bf2f(wc[OFF_BE4 + c]) - m4 * sc4;
            float m5 = stats[4096 + c] * inv;
            float v5 = fmaxf(stats[4352 + c] * inv - m5 * m5, 0.f);
            float sc5 = bf2f(wc[OFF_G5 + c]) * rsqrtf(v5 + EPSBN);
            float sh5 = bf2f(wc[OFF_BE5 + c]) - m5 * sc5;

            short8 r = ((const short8*)rec)[n8];
            short8 a = ((const short8*)c1)[n8];
            short8 b = ((const short8*)c2)[n8];
            float v[8];
            #pragma unroll
            for (int j = 0; j < 8; ++j) {
                v[j] = bfu((unsigned short)r[j]) * sc3 + sh3
                     + bfu((unsigned short)a[j]) * sc4 + sh4
                     + bfu((unsigned short)b[j]) * sc5 + sh5;
            }
            if (f) {
                float4* o = (float4*)out_;
                o[n8 * 2]     = make_float4(v[0], v[1], v[2], v[3]);
                o[n8 * 2 + 1] = make_float4(v[4], v[5], v[6], v[7]);
            } else {
                short8 o;
                #pragma unroll
                for (int j = 0; j < 8; ++j)
                    o[j] = (short)__bfloat16_as_ushort(__float2bfloat16(v[j]));
                ((short8*)out_)[n8] = o;
            }
        }
    }
}

// ---------------------------------------------------------------------------
// Workspace map (~40.2 MB used; ws is 256 MiB):
//   [0,4M): s spikes   [8,16M): l2   [16,24M): rec   [24,32M): c1
//   [32,40M): c2   [40M..): weight arena | stats(4608 fl) | flag | barrier
// ---------------------------------------------------------------------------
extern "C" void kernel_launch(void* const* d_in, const int* in_sizes, int n_in,
                              void* d_out, int out_size, void* d_ws, size_t ws_size,
                              hipStream_t stream) {
    char* ws = (char*)d_ws;
    unsigned char* s_u8  = (unsigned char*)ws;
    __hip_bfloat16* l2   = (__hip_bfloat16*)(ws + ((size_t)8 << 20));
    __hip_bfloat16* rec  = (__hip_bfloat16*)(ws + ((size_t)16 << 20));
    __hip_bfloat16* c1   = (__hip_bfloat16*)(ws + ((size_t)24 << 20));
    __hip_bfloat16* c2   = (__hip_bfloat16*)(ws + ((size_t)32 << 20));
    __hip_bfloat16* wc   = (__hip_bfloat16*)(ws + ((size_t)40 << 20));
    float* stats         = (float*)(ws + ((size_t)40 << 20) + (64 << 10));
    int* flag            = (int*)(ws + ((size_t)40 << 20) + (128 << 10));
    int* bar             = (int*)(ws + ((size_t)40 << 20) + (132 << 10));

    WPtrs wp;
    for (int i = 0; i < 15; ++i) wp.p[i] = d_in[i + 1];

    dim3 blk(256);
    k_init<<<dim3(45), blk, 0, stream>>>((const unsigned short*)d_in[0], wp, wc, stats, bar, flag);
    k_fused<<<dim3(NBLK), blk, 0, stream>>>(d_in[0], wc, stats, bar, flag,
                                            s_u8, l2, rec, c1, c2, d_out);
}

// Round 9
// 151.793 us; speedup vs baseline: 1.9924x; 1.9924x over previous
//
#include <hip/hip_runtime.h>
#include <hip/hip_bf16.h>

#define T_ 4
#define B_ 4
#define C_ 256
#define H_ 32
#define W_ 32
#define TB_ 16
#define Hh_ 16
#define Wh_ 16
#define INVS2 0.70710678118654752440f
#define EPSBN 1e-5f

typedef __attribute__((ext_vector_type(8))) short short8;
typedef __attribute__((ext_vector_type(4))) float f32x4;

__device__ inline float bf2f(__hip_bfloat16 v) { return __bfloat162float(v); }
__device__ inline float bfu(unsigned short u) { return __uint_as_float((unsigned)u << 16); }
// dual-path weight load: fp32 array or bf16 array, per flag
__device__ inline float wload(const void* p, int i, int f) {
    return f ? ((const float*)p)[i] : bf2f(((const __hip_bfloat16*)p)[i]);
}
__device__ inline unsigned short wbits(const void* p, int i, int f) {
    return f ? __bfloat16_as_ushort(__float2bfloat16(((const float*)p)[i]))
             : ((const unsigned short*)p)[i];
}

// ---------------------------------------------------------------------------
// K1: fused LIF + Haar-W. Planar coalesced uchar2 spikes; BN1 partial sums
// to race-free slots part1[c*32 + (b*2+half)*4 + j] (j: 0 sumL,1 ssL,2 sumH,
// 3 ssH). Each block self-sniffs dtype; block 0 publishes flag.
// ---------------------------------------------------------------------------
__global__ __launch_bounds__(256) void k_lifhaar(const void* __restrict__ x_,
                                                 unsigned char* __restrict__ s,
                                                 float* __restrict__ part1,
                                                 int* __restrict__ flag) {
    int bid = blockIdx.x;                      // 2048 = b(4) * c(256) * half(2)
    int tid = threadIdx.x;
    int lane = tid & 63, wv = tid >> 6;

    // self-sniff: bf16 N(0,1) never has exponent >= 134 (|v| >= 128)
    const unsigned short* xr = (const unsigned short*)x_;
    int cnt = 0;
    for (int i = tid; i < 2048; i += 256) {
        int e = (xr[i] >> 7) & 0xFF;
        if (e >= 134) cnt++;
    }
    for (int o = 1; o < 64; o <<= 1) cnt += __shfl_xor(cnt, o, 64);
    __shared__ int snif[4];
    if (lane == 0) snif[wv] = cnt;
    __syncthreads();
    int f = (snif[0] + snif[1] + snif[2] + snif[3] >= 32) ? 1 : 0;
    if (bid == 0 && tid == 0) *flag = f;

    int half = bid & 1;
    int c = (bid >> 1) & 255;
    int b = bid >> 9;
    int wp = tid & 15;
    int h = half * 16 + (tid >> 4);
    const float* xf = (const float*)x_;
    const unsigned int* xb = (const unsigned int*)x_;
    int n = ((b * 256 + c) * 32 + h) * 32 + 2 * wp;

    float v0 = 0.f, v1 = 0.f;
    float aL = 0.f, qL = 0.f, aH = 0.f, qH = 0.f;
    #pragma unroll
    for (int t = 0; t < T_; ++t) {
        size_t idx = (size_t)t * 1048576 + n;
        float x0, x1;
        if (f) {
            float2 xx = *(const float2*)(xf + idx);
            x0 = xx.x; x1 = xx.y;
        } else {
            unsigned int u = xb[idx >> 1];
            x0 = __uint_as_float(u << 16);
            x1 = __uint_as_float(u & 0xffff0000u);
        }
        v0 += (x0 - v0) * 0.5f;
        v1 += (x1 - v1) * 0.5f;
        float s0 = (v0 >= 1.f) ? 1.f : 0.f;
        float s1 = (v1 >= 1.f) ? 1.f : 0.f;
        v0 *= (1.f - s0);
        v1 *= (1.f - s1);
        int tb = t * 4 + b;
        ((uchar2*)s)[(size_t)(tb * 256 + c) * 512 + h * 16 + wp] =
            make_uchar2((unsigned char)s0, (unsigned char)s1);
        float cl = s0 + s1, ch = s0 - s1;
        aL += cl; qL += cl * cl; aH += ch; qH += ch * ch;
    }
    for (int o = 1; o < 64; o <<= 1) {
        aL += __shfl_xor(aL, o, 64); qL += __shfl_xor(qL, o, 64);
        aH += __shfl_xor(aH, o, 64); qH += __shfl_xor(qH, o, 64);
    }
    __shared__ float part[4][4];
    if (lane == 0) {
        part[wv][0] = aL; part[wv][1] = qL; part[wv][2] = aH; part[wv][3] = qH;
    }
    __syncthreads();
    if (tid < 4) {
        float tot = part[0][tid] + part[1][tid] + part[2][tid] + part[3][tid];
        part1[c * 32 + (b * 2 + half) * 4 + tid] = tot;   // race-free slot
    }
}

// ---------------------------------------------------------------------------
// K2: stage2 = BN1-apply + Haar-H + gates -> l2 bf16; BN2 partials to
// part2[c*128 + tb*8 + band*2 + w] (band LL,HL,LH,HH; w 0 sum,1 ss).
// ---------------------------------------------------------------------------
__global__ __launch_bounds__(256) void k_stage2(const unsigned char* __restrict__ s,
                                                const float* __restrict__ part1,
                                                const void* __restrict__ g1p,
                                                const void* __restrict__ be1p,
                                                const int* __restrict__ flag,
                                                float* __restrict__ part2,
                                                __hip_bfloat16* __restrict__ l2) {
    int blk = blockIdx.x;                 // TB*C = 4096
    int c = blk & 255;
    int tb = blk >> 8;
    int tid = threadIdx.x;
    int lane = tid & 63, wv = tid >> 6;
    int f = *flag;

    // reduce BN1 partials (8 slots x 4 components)
    __shared__ float ps[32];
    __shared__ float tot4[4];
    if (tid < 32) ps[tid] = part1[c * 32 + tid];
    __syncthreads();
    if (tid < 4) {
        float t = 0.f;
        #pragma unroll
        for (int k8 = 0; k8 < 8; ++k8) t += ps[k8 * 4 + tid];
        tot4[tid] = t;
    }
    __syncthreads();

    const float nrm = 1.f / 8192.f;
    float mL = tot4[0] * INVS2 * nrm;
    float vL = fmaxf(tot4[1] * 0.5f * nrm - mL * mL, 0.f);
    float sL = wload(g1p, c, f) * rsqrtf(vL + EPSBN);
    float tL = wload(be1p, c, f) - mL * sL;
    float mH = tot4[2] * INVS2 * nrm;
    float vH = fmaxf(tot4[3] * 0.5f * nrm - mH * mH, 0.f);
    float sH = wload(g1p, 256 + c, f) * rsqrtf(vH + EPSBN);
    float tH = wload(be1p, 256 + c, f) - mH * sH;
    float slo = sL * INVS2, shi = sH * INVS2;

    int w = tid & 15, v = tid >> 4;
    const uchar2* sp = (const uchar2*)(s + ((size_t)(tb * 256 + c)) * 1024);
    uchar2 pa = sp[(2 * v) * 16 + w];
    uchar2 pb = sp[(2 * v + 1) * 16 + w];
    float lt = (float)(pa.x + pa.y) * slo + tL;
    float lb = (float)(pb.x + pb.y) * slo + tL;
    float ht = (float)((int)pa.x - (int)pa.y) * shi + tH;
    float hb = (float)((int)pb.x - (int)pb.y) * shi + tH;

    float zLL = (lt + lb) * INVS2;
    float zHL = (lt - lb) * INVS2;
    float zLH = (ht + hb) * INVS2;
    float zHH = (ht - hb) * INVS2;
    zLL = (fabsf(zLL) - 0.5f >= 0.f) ? zLL : 0.f;
    zHL = (fabsf(zHL) - 0.5f >= 0.f) ? zHL : 0.f;
    zLH = (fabsf(zLH) - 0.5f >= 0.f) ? zLH : 0.f;
    zHH = (fabsf(zHH) - 0.5f >= 0.f) ? zHH : 0.f;

    float r0 = zLL, r1 = zHL, r2 = zLH, r3 = zHH;
    float q0 = zLL * zLL, q1 = zHL * zHL, q2 = zLH * zLH, q3 = zHH * zHH;
    for (int o = 1; o < 64; o <<= 1) {
        r0 += __shfl_xor(r0, o, 64); r1 += __shfl_xor(r1, o, 64);
        r2 += __shfl_xor(r2, o, 64); r3 += __shfl_xor(r3, o, 64);
        q0 += __shfl_xor(q0, o, 64); q1 += __shfl_xor(q1, o, 64);
        q2 += __shfl_xor(q2, o, 64); q3 += __shfl_xor(q3, o, 64);
    }
    __shared__ float part[4][8];
    if (lane == 0) {
        part[wv][0] = r0; part[wv][1] = r1; part[wv][2] = r2; part[wv][3] = r3;
        part[wv][4] = q0; part[wv][5] = q1; part[wv][6] = q2; part[wv][7] = q3;
    }
    __syncthreads();
    float S0 = part[0][0] + part[1][0] + part[2][0] + part[3][0];
    float S1 = part[0][1] + part[1][1] + part[2][1] + part[3][1];
    float S2 = part[0][2] + part[1][2] + part[2][2] + part[3][2];
    float S3 = part[0][3] + part[1][3] + part[2][3] + part[3][3];
    float Q0 = part[0][4] + part[1][4] + part[2][4] + part[3][4];
    float Q1 = part[0][5] + part[1][5] + part[2][5] + part[3][5];
    float Q2 = part[0][6] + part[1][6] + part[2][6] + part[3][6];
    float Q3 = part[0][7] + part[1][7] + part[2][7] + part[3][7];
    float fLL = (Q0 * (1.f / 256.f) > 0.01f) ? 1.f : 0.f;
    float fHL = (Q1 * (1.f / 256.f) > 0.02f) ? 1.f : 0.f;
    float fLH = (Q2 * (1.f / 256.f) > 0.02f) ? 1.f : 0.f;
    float fHH = (Q3 * (1.f / 256.f) > 0.05f) ? 1.f : 0.f;

    if (tid < 8) {
        const float vals[8] = {fLL * S0, fLL * Q0, fHL * S1, fHL * Q1,
                               fLH * S2, fLH * Q2, fHH * S3, fHH * Q3};
        part2[c * 128 + tb * 8 + tid] = vals[tid];        // race-free slot
    }

    size_t ob = (((size_t)tb * 1024) + c) * 256 + tid;
    l2[ob]               = __float2bfloat16(zLL * fLL);
    l2[ob + 256u * 256u] = __float2bfloat16(zHL * fHL);
    l2[ob + 512u * 256u] = __float2bfloat16(zLH * fLH);
    l2[ob + 768u * 256u] = __float2bfloat16(zHH * fHH);
}

// ---------------------------------------------------------------------------
// K3: convmix. bids [0,256) = conv (MFMA implicit GEMM, BN4/5 partials to
// part45[ch*64 + tb*4 + which]); bids [256,512) = mixinv (BN2-apply + block
// matmul + inverse Haar -> rec, BN3 partials to part3[ch*32 + tb*2 + w]).
// ---------------------------------------------------------------------------
struct SharedU {
    union {
        struct {
            short lo[1025 * 8];            // channel-last bf16, d 0..7 (+zero row)
            short hi[1025 * 8];            // d 8..15
            unsigned short w2s[2304];      // [k][d*9+tap]
            unsigned short w1s[256];       // [k][d]
            unsigned short bs[32];         // B1 | B2
            float parts[4][4][16];         // [wv][g][r*4+which]
        } cv;
        struct {
            float wt[4][16][16];           // [q][d][k]
            float bsc[64], bsh[64];
            float red2[128];               // BN2 reduce staging
            float parts2[4][32];
        } mi;
    };
};

__global__ __launch_bounds__(256) void k_convmix(const unsigned char* __restrict__ s,
                                                 const __hip_bfloat16* __restrict__ l2,
                                                 const void* __restrict__ hwp,
                                                 const void* __restrict__ w1p,
                                                 const void* __restrict__ b1p,
                                                 const void* __restrict__ w2p,
                                                 const void* __restrict__ b2p,
                                                 const void* __restrict__ g2p,
                                                 const void* __restrict__ be2p,
                                                 const int* __restrict__ flag,
                                                 const float* __restrict__ part2,
                                                 float* __restrict__ part3,
                                                 float* __restrict__ part45,
                                                 __hip_bfloat16* __restrict__ rec,
                                                 __hip_bfloat16* __restrict__ c1,
                                                 __hip_bfloat16* __restrict__ c2) {
    __shared__ SharedU sm;
    int bid = blockIdx.x;
    int tid = threadIdx.x;
    int lane = tid & 63, wv = tid >> 6;
    int f = *flag;

    if (bid < 256) {
        // ------------------------------ conv role ------------------------------
        int img = bid;
        for (int i = tid; i < 2304; i += 256) sm.cv.w2s[i] = wbits(w2p, i, f);
        sm.cv.w1s[tid] = wbits(w1p, tid, f);
        if (tid < 16) { sm.cv.bs[tid] = wbits(b1p, tid, f); sm.cv.bs[16 + tid] = wbits(b2p, tid, f); }
        if (tid < 8) {
            ((unsigned int*)sm.cv.lo)[4096 + (tid & 3)] = 0;
            ((unsigned int*)sm.cv.hi)[4096 + (tid & 3)] = 0;
        }
        {
            const unsigned int* sp = (const unsigned int*)(s + (size_t)img * 16384);
            int d2 = tid >> 5;
            int pg = tid & 31;
            unsigned int* dst = (unsigned int*)((d2 < 4) ? sm.cv.lo : sm.cv.hi);
            int dl = d2 & 3;
            #pragma unroll
            for (int p = 0; p < 8; ++p) {
                int base = p * 32 + pg;
                unsigned int u0 = sp[d2 * 512 + base];
                unsigned int u1 = sp[d2 * 512 + 256 + base];
                #pragma unroll
                for (int jj = 0; jj < 4; ++jj) {
                    int j = (jj + pg) & 3;
                    unsigned int b0 = (u0 >> (8 * j)) & 255u;
                    unsigned int b1 = (u1 >> (8 * j)) & 255u;
                    unsigned int val = (b0 ? 0x3F80u : 0u) | ((b1 ? 0x3F80u : 0u) << 16);
                    int pix = p * 128 + pg * 4 + j;
                    dst[pix * 4 + dl] = val;
                }
            }
        }
        __syncthreads();

        int m = lane & 15;
        int g = lane >> 4;
        const int tapA[5] = {0, 2, 4, 6, 8};
        const int tapB[5] = {1, 3, 5, 7, 8};

        short8 afr[5], a1f;
        #pragma unroll
        for (int p = 0; p < 5; ++p) {
            int tap = (g < 2) ? tapA[p] : tapB[p];
            short8 av;
            #pragma unroll
            for (int j = 0; j < 8; ++j) {
                int d = (g & 1) * 8 + j;
                unsigned short w = sm.cv.w2s[m * 144 + d * 9 + tap];
                if (p == 4 && g >= 2) w = 0;
                av[j] = (short)w;
            }
            afr[p] = av;
        }
        #pragma unroll
        for (int j = 0; j < 8; ++j) {
            int d = (g & 1) * 8 + j;
            a1f[j] = (g < 2) ? (short)sm.cv.w1s[m * 16 + d] : (short)0;
        }
        float bias1[4], bias2[4];
        #pragma unroll
        for (int r = 0; r < 4; ++r) {
            bias1[r] = bfu(sm.cv.bs[g * 4 + r]);
            bias2[r] = bfu(sm.cv.bs[16 + g * 4 + r]);
        }

        __hip_bfloat16* o1 = c1 + (size_t)img * 16384;
        __hip_bfloat16* o2 = c2 + (size_t)img * 16384;
        const short* bsrc = (g & 1) ? sm.cv.hi : sm.cv.lo;

        float cs1[4] = {0, 0, 0, 0}, cq1[4] = {0, 0, 0, 0};
        float cs2[4] = {0, 0, 0, 0}, cq2[4] = {0, 0, 0, 0};

        for (int t = wv * 16; t < wv * 16 + 16; ++t) {
            int h = t >> 1;
            int w0 = (t & 1) << 4;
            f32x4 acc2 = {0.f, 0.f, 0.f, 0.f};
            f32x4 acc1 = {0.f, 0.f, 0.f, 0.f};
            #pragma unroll
            for (int p = 0; p < 5; ++p) {
                int tap = (g < 2) ? tapA[p] : tapB[p];
                int row = h + tap / 3 - 1;
                int col = w0 + m + (tap % 3) - 1;
                bool ok = ((unsigned)row < 32u) && ((unsigned)col < 32u);
                int idx = ok ? (row * 32 + col) : 1024;
                short8 bv = *(const short8*)&bsrc[idx * 8];
                acc2 = __builtin_amdgcn_mfma_f32_16x16x32_bf16(afr[p], bv, acc2, 0, 0, 0);
                if (p == 2)
                    acc1 = __builtin_amdgcn_mfma_f32_16x16x32_bf16(a1f, bv, acc1, 0, 0, 0);
            }
            int pix = h * 32 + w0 + m;
            #pragma unroll
            for (int r = 0; r < 4; ++r) {
                int k = g * 4 + r;
                float y1 = acc1[r] + bias1[r];
                float y2 = acc2[r] + bias2[r];
                o1[(size_t)k * 1024 + pix] = __float2bfloat16(y1);
                o2[(size_t)k * 1024 + pix] = __float2bfloat16(y2);
                cs1[r] += y1; cq1[r] += y1 * y1;
                cs2[r] += y2; cq2[r] += y2 * y2;
            }
        }
        #pragma unroll
        for (int o = 1; o < 16; o <<= 1) {
            #pragma unroll
            for (int r = 0; r < 4; ++r) {
                cs1[r] += __shfl_xor(cs1[r], o, 64);
                cq1[r] += __shfl_xor(cq1[r], o, 64);
                cs2[r] += __shfl_xor(cs2[r], o, 64);
                cq2[r] += __shfl_xor(cq2[r], o, 64);
            }
        }
        if (m == 0) {
            #pragma unroll
            for (int r = 0; r < 4; ++r) {
                sm.cv.parts[wv][g][r * 4 + 0] = cs1[r];
                sm.cv.parts[wv][g][r * 4 + 1] = cq1[r];
                sm.cv.parts[wv][g][r * 4 + 2] = cs2[r];
                sm.cv.parts[wv][g][r * 4 + 3] = cq2[r];
            }
        }
        __syncthreads();
        if (tid < 64) {
            int gg = tid >> 4, r = (tid >> 2) & 3, which = tid & 3;
            float tot = sm.cv.parts[0][gg][r * 4 + which] + sm.cv.parts[1][gg][r * 4 + which]
                      + sm.cv.parts[2][gg][r * 4 + which] + sm.cv.parts[3][gg][r * 4 + which];
            int ch = (img & 15) * 16 + gg * 4 + r;
            part45[ch * 64 + (img >> 4) * 4 + which] = tot;   // race-free slot
        }
    } else {
        // ------------------------------ mixinv role ------------------------------
        int mb = bid - 256;
        int cg = mb & 15;
        int tb = mb >> 4;

        for (int i = tid; i < 1024; i += 256) {
            int q = i >> 8, rem = i & 255, d = rem >> 4, k = rem & 15;
            int nb = q * 4 + (cg >> 2);
            sm.mi.wt[q][d][k] = wload(hwp, nb * 256 + d * 16 + k, f);
        }
        // reduce BN2 partials over tb: 128 combos (q,d,w)
        if (tid < 128) {
            int q = tid >> 5, rest = tid & 31, d = rest >> 1, w = rest & 1;
            int cl = cg * 16 + d;
            float acc = 0.f;
            #pragma unroll
            for (int t2 = 0; t2 < 16; ++t2)
                acc += part2[cl * 128 + t2 * 8 + q * 2 + w];
            sm.mi.red2[q * 32 + d * 2 + w] = acc;
        }
        __syncthreads();
        if (tid < 64) {
            int q = tid >> 4, d = tid & 15;
            int ch = q * 256 + cg * 16 + d;
            float S = sm.mi.red2[q * 32 + d * 2];
            float Q = sm.mi.red2[q * 32 + d * 2 + 1];
            float m = S * (1.f / 4096.f);
            float var = fmaxf(Q * (1.f / 4096.f) - m * m, 0.f);
            float sc = wload(g2p, ch, f) * rsqrtf(var + EPSBN);
            sm.mi.bsc[tid] = sc;
            sm.mi.bsh[tid] = wload(be2p, ch, f) - m * sc;
        }
        __syncthreads();

        float h[4][16];
        #pragma unroll
        for (int q = 0; q < 4; ++q)
            #pragma unroll
            for (int k = 0; k < 16; ++k) h[q][k] = 0.f;

        int p = tid;
        #pragma unroll
        for (int q = 0; q < 4; ++q) {
            const __hip_bfloat16* base =
                l2 + ((size_t)tb * 1024 + q * 256 + cg * 16) * 256 + p;
            #pragma unroll
            for (int d = 0; d < 16; ++d) {
                float xv = bf2f(base[d * 256]) * sm.mi.bsc[q * 16 + d] + sm.mi.bsh[q * 16 + d];
                #pragma unroll
                for (int k = 0; k < 16; ++k)
                    h[q][k] = fmaf(xv, sm.mi.wt[q][d][k], h[q][k]);
            }
        }

        int uh = tid >> 4, uw = tid & 15;
        __hip_bfloat16* ob = rec + ((size_t)tb * 256 + cg * 16) * 1024;
        float sk[16], qk[16];
        #pragma unroll
        for (int k = 0; k < 16; ++k) {
            float LL = h[0][k], HL = h[1][k], LH = h[2][k], HH = h[3][k];
            float v00 = 0.5f * (LL + HL + LH + HH);
            float v01 = 0.5f * (LL + HL - LH - HH);
            float v10 = 0.5f * (LL - HL + LH - HH);
            float v11 = 0.5f * (LL - HL - LH + HH);
            __hip_bfloat162 top, bot;
            top.x = __float2bfloat16(v00); top.y = __float2bfloat16(v01);
            bot.x = __float2bfloat16(v10); bot.y = __float2bfloat16(v11);
            *(__hip_bfloat162*)(ob + (size_t)k * 1024 + (2 * uh) * 32 + 2 * uw) = top;
            *(__hip_bfloat162*)(ob + (size_t)k * 1024 + (2 * uh + 1) * 32 + 2 * uw) = bot;
            sk[k] = v00 + v01 + v10 + v11;
            qk[k] = v00 * v00 + v01 * v01 + v10 * v10 + v11 * v11;
        }
        for (int o = 1; o < 64; o <<= 1) {
            #pragma unroll
            for (int k = 0; k < 16; ++k) {
                sk[k] += __shfl_xor(sk[k], o, 64);
                qk[k] += __shfl_xor(qk[k], o, 64);
            }
        }
        if (lane == 0) {
            #pragma unroll
            for (int k = 0; k < 16; ++k) {
                sm.mi.parts2[wv][k * 2]     = sk[k];
                sm.mi.parts2[wv][k * 2 + 1] = qk[k];
            }
        }
        __syncthreads();
        if (tid < 32) {
            int k = tid >> 1, w = tid & 1;
            float tot = sm.mi.parts2[0][tid] + sm.mi.parts2[1][tid]
                      + sm.mi.parts2[2][tid] + sm.mi.parts2[3][tid];
            part3[(cg * 16 + k) * 32 + tb * 2 + w] = tot;     // race-free slot
        }
    }
}

// ---------------------------------------------------------------------------
// K4: final combine. Block covers 2048 elems = 2 channels; threads 0/1
// reduce the BN3/4/5 partials for their channel and derive coefficients.
// FIX (R8 bug): channel must be masked & 255 — layout (TB,C,H,W) wraps the
// channel every 256; unmasked c read OOB poison -> rstd=316 blowup.
// ---------------------------------------------------------------------------
__global__ __launch_bounds__(256) void k_final(const __hip_bfloat16* __restrict__ rec,
                                               const __hip_bfloat16* __restrict__ c1,
                                               const __hip_bfloat16* __restrict__ c2,
                                               const float* __restrict__ part3,
                                               const float* __restrict__ part45,
                                               const void* __restrict__ g3p, const void* __restrict__ be3p,
                                               const void* __restrict__ g4p, const void* __restrict__ be4p,
                                               const void* __restrict__ g5p, const void* __restrict__ be5p,
                                               const int* __restrict__ flag,
                                               void* __restrict__ out_) {
    int bid = blockIdx.x;                 // 2048
    int tid = threadIdx.x;
    int f = *flag;

    __shared__ float coef[2][6];
    if (tid < 2) {
        int c = (bid * 2 + tid) & 255;    // <-- THE FIX
        float S3 = 0.f, Q3 = 0.f, S4 = 0.f, Q4 = 0.f, S5 = 0.f, Q5 = 0.f;
        #pragma unroll
        for (int t2 = 0; t2 < 16; ++t2) {
            S3 += part3[c * 32 + t2 * 2];
            Q3 += part3[c * 32 + t2 * 2 + 1];
            S4 += part45[c * 64 + t2 * 4];
            Q4 += part45[c * 64 + t2 * 4 + 1];
            S5 += part45[c * 64 + t2 * 4 + 2];
            Q5 += part45[c * 64 + t2 * 4 + 3];
        }
        const float inv = 1.f / 16384.f;
        float m3 = S3 * inv, v3 = fmaxf(Q3 * inv - m3 * m3, 0.f);
        float sc3 = wload(g3p, c, f) * rsqrtf(v3 + EPSBN);
        float m4 = S4 * inv, v4 = fmaxf(Q4 * inv - m4 * m4, 0.f);
        float sc4 = wload(g4p, c, f) * rsqrtf(v4 + EPSBN);
        float m5 = S5 * inv, v5 = fmaxf(Q5 * inv - m5 * m5, 0.f);
        float sc5 = wload(g5p, c, f) * rsqrtf(v5 + EPSBN);
        coef[tid][0] = sc3; coef[tid][1] = wload(be3p, c, f) - m3 * sc3;
        coef[tid][2] = sc4; coef[tid][3] = wload(be4p, c, f) - m4 * sc4;
        coef[tid][4] = sc5; coef[tid][5] = wload(be5p, c, f) - m5 * sc5;
    }
    __syncthreads();

    int n8 = bid * 256 + tid;             // 8 bf16 elems per thread
    int cl = (tid >> 7) & 1;              // second half of block = channel +1
    float sc3 = coef[cl][0], sh3 = coef[cl][1];
    float sc4 = coef[cl][2], sh4 = coef[cl][3];
    float sc5 = coef[cl][4], sh5 = coef[cl][5];

    short8 r = ((const short8*)rec)[n8];
    short8 a = ((const short8*)c1)[n8];
    short8 b = ((const short8*)c2)[n8];
    float v[8];
    #pragma unroll
    for (int j = 0; j < 8; ++j) {
        v[j] = bfu((unsigned short)r[j]) * sc3 + sh3
             + bfu((unsigned short)a[j]) * sc4 + sh4
             + bfu((unsigned short)b[j]) * sc5 + sh5;
    }
    if (f) {
        float4* o = (float4*)out_;
        o[n8 * 2]     = make_float4(v[0], v[1], v[2], v[3]);
        o[n8 * 2 + 1] = make_float4(v[4], v[5], v[6], v[7]);
    } else {
        short8 o;
        #pragma unroll
        for (int j = 0; j < 8; ++j)
            o[j] = (short)__bfloat16_as_ushort(__float2bfloat16(v[j]));
        ((short8*)out_)[n8] = o;
    }
}

// ---------------------------------------------------------------------------
// Workspace map (~40.5 MB used; ws = 256 MiB):
//   [0,4M): s spikes   [8,16M): l2   [16,24M): rec   [24,32M): c1
//   [32,40M): c2
//   [40M+0K):  part1 (8192 fl)   [40M+64K): part2 (32768 fl)
//   [40M+256K): part3 (8192 fl)  [40M+320K): part45 (16384 fl)
//   [40M+448K): flag
// All partial slots are fully written before read -> no zero-init needed.
// ---------------------------------------------------------------------------
extern "C" void kernel_launch(void* const* d_in, const int* in_sizes, int n_in,
                              void* d_out, int out_size, void* d_ws, size_t ws_size,
                              hipStream_t stream) {
    char* ws = (char*)d_ws;
    unsigned char* s_u8  = (unsigned char*)ws;
    __hip_bfloat16* l2   = (__hip_bfloat16*)(ws + ((size_t)8 << 20));
    __hip_bfloat16* rec  = (__hip_bfloat16*)(ws + ((size_t)16 << 20));
    __hip_bfloat16* c1   = (__hip_bfloat16*)(ws + ((size_t)24 << 20));
    __hip_bfloat16* c2   = (__hip_bfloat16*)(ws + ((size_t)32 << 20));
    float* part1         = (float*)(ws + ((size_t)40 << 20));
    float* part2         = (float*)(ws + ((size_t)40 << 20) + (64 << 10));
    float* part3         = (float*)(ws + ((size_t)40 << 20) + (256 << 10));
    float* part45        = (float*)(ws + ((size_t)40 << 20) + (320 << 10));
    int* flag            = (int*)(ws + ((size_t)40 << 20) + (448 << 10));

    dim3 blk(256);
    k_lifhaar<<<dim3(2048), blk, 0, stream>>>(d_in[0], s_u8, part1, flag);
    k_stage2<<<dim3(4096), blk, 0, stream>>>(s_u8, part1, d_in[6], d_in[7],
                                             flag, part2, l2);
    k_convmix<<<dim3(512), blk, 0, stream>>>(s_u8, l2, d_in[1], d_in[2], d_in[3],
                                             d_in[4], d_in[5], d_in[8], d_in[9],
                                             flag, part2, part3, part45, rec, c1, c2);
    k_final<<<dim3(2048), blk, 0, stream>>>(rec, c1, c2, part3, part45,
                                            d_in[10], d_in[11], d_in[12], d_in[13],
                                            d_in[14], d_in[15], flag, d_out);
}